// Round 5
// baseline (209.480 us; speedup 1.0000x reference)
//
#include <hip/hip_runtime.h>
#include <stdint.h>

// LocalContrastiveLoss: exact reproduction of the JAX reference, including
// threefry2x32 PRNG (partitionable mode — verified bit-exact, absmax 0) and
// lax.top_k tie-breaking (lower index wins on equal values).
//
// Shapes: features (B=8, C=256, H=128, W=128) f32; labels (8,128,128) i32.
// Output: single f32 scalar.
//
// R5 structure: ONE kernel, 160 blocks x 512 thr.
//   Phase 1 (all 160 blocks, one per (s,b,c)): top-3 + counts, fused gather +
//     L2-normalize of the block's 3 sampled vectors, then RELEASE flags1[g]=1.
//   Phase 2 (blocks 0..95 = (b,c,p)): ACQUIRE-spin on all 160 flags1, then
//     42-slot dot reduction (mu folded in: dot(a,unit(mean v)) =
//     (a.Sv)/3 / max(|Sv|/3,eps)), masked log terms -> partials[g],
//     RELEASE flags2[g]=1.
//   Phase 3 (block 0): ACQUIRE-spin on 96 flags2, deterministic tree sum,
//     write the scalar.
// Handshake safety: 160 blocks <= 256 CUs so the whole grid is co-resident
// (no spin deadlock). Flags use sentinel ==1; d_ws is re-poisoned 0xAAAAAAAA
// before every launch so no zero-init is needed (avoids an init race).

namespace {

constexpr int Nn = 16384;   // H*W

// ---------------- threefry2x32 (matches jax/_src/prng.py exactly) ----------
__device__ __forceinline__ uint32_t rotl32(uint32_t v, int d) {
  return (v << d) | (v >> (32 - d));
}

__device__ __forceinline__ void threefry2x32(uint32_t k0, uint32_t k1,
                                             uint32_t x0, uint32_t x1,
                                             uint32_t& o0, uint32_t& o1) {
  uint32_t ks2 = k0 ^ k1 ^ 0x1BD11BDAu;
  x0 += k0; x1 += k1;
#define TF_R(d) { x0 += x1; x1 = rotl32(x1, (d)); x1 ^= x0; }
  TF_R(13) TF_R(15) TF_R(26) TF_R(6)
  x0 += k1; x1 += ks2 + 1u;
  TF_R(17) TF_R(29) TF_R(16) TF_R(24)
  x0 += ks2; x1 += k0 + 2u;
  TF_R(13) TF_R(15) TF_R(26) TF_R(6)
  x0 += k0; x1 += k1 + 3u;
  TF_R(17) TF_R(29) TF_R(16) TF_R(24)
  x0 += k1; x1 += ks2 + 4u;
  TF_R(13) TF_R(15) TF_R(26) TF_R(6)
  x0 += ks2; x1 += k0 + 5u;
#undef TF_R
  o0 = x0; o1 = x1;
}

// insert candidate into sorted (descending) top-3 list; key==0 never inserts
__device__ __forceinline__ void ins3(unsigned long long t[3], unsigned long long k) {
  if (k > t[0])      { t[2] = t[1]; t[1] = t[0]; t[0] = k; }
  else if (k > t[1]) { t[2] = t[1]; t[1] = k; }
  else if (k > t[2]) { t[2] = k; }
}

__device__ __forceinline__ void release_flag(int* f) {
  __threadfence();
  __hip_atomic_store(f, 1, __ATOMIC_RELEASE, __HIP_MEMORY_SCOPE_AGENT);
}

__device__ __forceinline__ void acquire_spin(const int* f) {
  while (__hip_atomic_load(f, __ATOMIC_ACQUIRE, __HIP_MEMORY_SCOPE_AGENT) != 1) {
    __builtin_amdgcn_s_sleep(2);
  }
}

// ---------------- fused kernel ---------------------------------------------
// fnorm layout: [(s*32 + b*4 + c)*3 + r]*256 + ch,  s: 0=pos1, 1=neg1,
// 2=pos2-anchors, 3=mu2-source, 4=neg2.
__global__ void fused_kernel(const int4* __restrict__ labels4,
                             const float* __restrict__ feat,
                             int* __restrict__ counts,
                             float* __restrict__ fnorm,
                             int* __restrict__ flags1,
                             int* __restrict__ flags2,
                             float* __restrict__ partials,
                             float* __restrict__ out) {
  const int g = blockIdx.x;          // 160: g = s*32 + b*4 + c
  const int tid = threadIdx.x;
  const int lane = tid & 63;
  const int wave = tid >> 6;

  // ===================== Phase 1: top-3 + counts + gather ==================
  {
    const int s = g >> 5;
    const int b = (g >> 2) & 7;
    const int c = g & 3;

    // subkey = jax.random.split(key(42), 5)[s]
    uint32_t sk0, sk1;
    threefry2x32(0u, 42u, 0u, (uint32_t)s, sk0, sk1);

    // Packed rank key: (uniform_float_bits << 32) | (0xFFFFFFFF - pixel_idx).
    // float bits ((bits>>9)|0x3f800000) are monotone in the uniform value;
    // the complemented index reproduces lax.top_k's lower-index-wins tie
    // rule. Branchless threefry (exec-mask makes conditional cost the same).
    unsigned long long t[3] = {0ull, 0ull, 0ull};
    int cnt = 0;
    const int4* row = labels4 + b * (Nn / 4);
    const uint32_t jbase = (uint32_t)((b * 4 + c) * Nn);
#pragma unroll 4
    for (int it = 0; it < 8; ++it) {           // 512 thr x 8 = 4096 int4
      const int i4 = tid + it * 512;
      const int4 L = row[i4];
      const int la[4] = {L.x, L.y, L.z, L.w};
#pragma unroll
      for (int e = 0; e < 4; ++e) {
        const uint32_t n = (uint32_t)(i4 * 4 + e);
        uint32_t r0, r1;
        threefry2x32(sk0, sk1, 0u, jbase + n, r0, r1);
        const uint32_t bits = r0 ^ r1;                 // partitionable draw
        const uint32_t fb = (bits >> 9) | 0x3f800000u; // uniform bits [1,2)
        const bool m = (la[e] == c);
        const unsigned long long key =
            m ? (((unsigned long long)fb << 32) |
                 (unsigned long long)(0xFFFFFFFFu - n))
              : 0ull;
        cnt += m ? 1 : 0;
        ins3(t, key);
      }
    }

    // wave (64-lane) reduction, then 8-wave merge
    for (int off = 32; off > 0; off >>= 1) {
      unsigned long long o0 = __shfl_down(t[0], (unsigned)off);
      unsigned long long o1 = __shfl_down(t[1], (unsigned)off);
      unsigned long long o2 = __shfl_down(t[2], (unsigned)off);
      int oc = __shfl_down(cnt, (unsigned)off);
      ins3(t, o0); ins3(t, o1); ins3(t, o2);
      cnt += oc;
    }
    __shared__ unsigned long long sm[8][3];
    __shared__ int sc[8];
    __shared__ int sidx[3];
    __shared__ float sr[4][3];
    if (lane == 0) { sm[wave][0] = t[0]; sm[wave][1] = t[1]; sm[wave][2] = t[2]; sc[wave] = cnt; }
    __syncthreads();
    if (tid == 0) {
      unsigned long long f[3] = {sm[0][0], sm[0][1], sm[0][2]};
      int tot = sc[0];
      for (int w = 1; w < 8; ++w) {
        ins3(f, sm[w][0]); ins3(f, sm[w][1]); ins3(f, sm[w][2]);
        tot += sc[w];
      }
#pragma unroll
      for (int r = 0; r < 3; ++r) {
        // empty slot (key==0): index irrelevant (masked downstream), use 0
        sidx[r] = (f[r] == 0ull) ? 0
                  : (int)(0xFFFFFFFFu - (uint32_t)(f[r] & 0xFFFFFFFFull));
      }
      if (s == 0) counts[b * 4 + c] = tot;
    }
    __syncthreads();

    // fused gather + per-pixel L2 normalize (threads 0..255; waves 0..3)
    float v[3];
    if (tid < 256) {
      const int ch = tid;
      float ss[3];
#pragma unroll
      for (int r = 0; r < 3; ++r) {
        v[r] = feat[((b << 8) + ch) * Nn + sidx[r]];
        ss[r] = v[r] * v[r];
      }
      for (int off = 32; off > 0; off >>= 1) {
#pragma unroll
        for (int r = 0; r < 3; ++r) ss[r] += __shfl_down(ss[r], (unsigned)off);
      }
      if (lane == 0) {
#pragma unroll
        for (int r = 0; r < 3; ++r) sr[wave][r] = ss[r];
      }
    }
    __syncthreads();
    if (tid < 256) {
      const int ch = tid;
#pragma unroll
      for (int r = 0; r < 3; ++r) {
        const float nrm = fmaxf(sqrtf(sr[0][r] + sr[1][r] + sr[2][r] + sr[3][r]), 1e-12f);
        fnorm[(g * 3 + r) * 256 + ch] = v[r] / nrm;
      }
    }
    __syncthreads();
    if (tid == 0) release_flag(&flags1[g]);    // publish fnorm + counts
  }

  if (g >= 96) return;                          // phase-1-only blocks done

  // ===================== Phase 2: loss terms (blocks 0..95) ================
  {
    // wait for the whole grid's fnorm/counts
    if (tid < 160) acquire_spin(&flags1[tid]);
    __syncthreads();

    const int b = g / 12;
    const int c = (g % 12) / 3;
    const int p = g % 3;
    const int bc = b * 4 + c;
    __shared__ float red[4][42];

    if (tid < 256) {
      const int ch = tid;
      const float a1 = fnorm[(bc * 3 + p) * 256 + ch];           // s=0 anchor
      const float a2 = fnorm[((64 + bc) * 3 + p) * 256 + ch];    // s=2 anchor

      // f1sum = sum of the 3 normalized s=0 vectors of (b,c)
      const float f1 = fnorm[(bc * 3 + 0) * 256 + ch] +
                       fnorm[(bc * 3 + 1) * 256 + ch] +
                       fnorm[(bc * 3 + 2) * 256 + ch];

      float part[42];
      part[0] = a1 * f1;                  // a1 . f1sum
      part[1] = f1 * f1;                  // ||f1sum||^2
      // [2..13] dot(a1, neg1[b,e,k])   (s=1)
#pragma unroll
      for (int e = 0; e < 4; ++e)
#pragma unroll
        for (int k = 0; k < 3; ++k)
          part[2 + e * 3 + k] = a1 * fnorm[((32 + b * 4 + e) * 3 + k) * 256 + ch];
      // [14..29] per b2: a2 . f2sum[b2], ||f2sum[b2]||^2   (s=3)
#pragma unroll
      for (int b2 = 0; b2 < 8; ++b2) {
        const int ib = (96 + b2 * 4 + c) * 3;
        const float f2 = fnorm[(ib + 0) * 256 + ch] +
                         fnorm[(ib + 1) * 256 + ch] +
                         fnorm[(ib + 2) * 256 + ch];
        part[14 + 2 * b2]     = a2 * f2;
        part[14 + 2 * b2 + 1] = f2 * f2;
      }
      // [30..41] dot(a2, neg2[b,e,k])  (s=4)
#pragma unroll
      for (int e = 0; e < 4; ++e)
#pragma unroll
        for (int k = 0; k < 3; ++k)
          part[30 + e * 3 + k] = a2 * fnorm[((128 + b * 4 + e) * 3 + k) * 256 + ch];

      for (int off = 32; off > 0; off >>= 1) {
#pragma unroll
        for (int i = 0; i < 42; ++i) part[i] += __shfl_down(part[i], (unsigned)off);
      }
      if (lane == 0) {
#pragma unroll
        for (int i = 0; i < 42; ++i) red[wave][i] = part[i];
      }
    }
    __syncthreads();

    if (tid == 0) {
      float d[42];
#pragma unroll
      for (int i = 0; i < 42; ++i) d[i] = red[0][i] + red[1][i] + red[2][i] + red[3][i];

      int cb[4];
      for (int e = 0; e < 4; ++e) cb[e] = counts[b * 4 + e];
      bool has_neg = false;
      for (int e = 0; e < 4; ++e) if (e != c && cb[e] > 0) has_neg = true;
      const bool valid_anchor = (cb[c] >= 3) && has_neg;

      float sn1 = 0.f, sn2 = 0.f;
      for (int e = 0; e < 4; ++e) {
        if (e == c) continue;
        int km = cb[e] < 3 ? cb[e] : 3;
        for (int k = 0; k < km; ++k) {
          sn1 += expf(d[2 + e * 3 + k] * 10.0f);
          sn2 += expf(d[30 + e * 3 + k] * 10.0f);
        }
      }
      float term = 0.f;
      if (valid_anchor) {
        // dot(a1, mu1) = (a1.f1sum)/3 / max(||f1sum||/3, eps)
        const float d0 = (d[0] / 3.0f) / fmaxf(sqrtf(d[1]) / 3.0f, 1e-8f);
        const float sp1 = expf(d0 * 10.0f);
        term -= logf(sp1 / (sp1 + sn1 + 1e-8f));
        for (int b2 = 0; b2 < 8; ++b2) {
          if (b2 == b) continue;
          if (counts[b2 * 4 + c] >= 3) {
            const float d2 = (d[14 + 2 * b2] / 3.0f) /
                             fmaxf(sqrtf(d[14 + 2 * b2 + 1]) / 3.0f, 1e-8f);
            const float sp2 = expf(d2 * 10.0f);
            term -= logf(sp2 / (sp2 + sn2 + 1e-8f));
          }
        }
      }
      partials[g] = term;
      release_flag(&flags2[g]);
    }
  }

  if (g != 0) return;

  // ===================== Phase 3: deterministic final sum (block 0) ========
  {
    if (tid < 96) acquire_spin(&flags2[tid]);
    // each spinning thread acquired the flag pairing with its own partials[t]
    float v = (tid < 96) ? partials[tid] : 0.f;
    for (int off = 32; off > 0; off >>= 1) v += __shfl_down(v, (unsigned)off);
    __shared__ float s2[2];
    if (lane == 0 && wave < 2) s2[wave] = v;
    __syncthreads();
    if (tid == 0) {
      const double total = (double)s2[0] + (double)s2[1];
      out[0] = (float)(0.1 * total / (24.0 + 1e-8));  // LAM*loss/(B*P+EPS)
    }
  }
}

}  // namespace

extern "C" void kernel_launch(void* const* d_in, const int* in_sizes, int n_in,
                              void* d_out, int out_size, void* d_ws, size_t ws_size,
                              hipStream_t stream) {
  const float* feat = (const float*)d_in[0];
  const int* labels = (const int*)d_in[1];
  float* out = (float*)d_out;
  char* ws = (char*)d_ws;

  // workspace layout (bytes):
  //   [0, 128)             counts  : 8*4 int32 class counts
  //   [1024, 492544)       fnorm   : 480*256 f32 normalized sampled vectors
  //   [492544, 493184)     flags1  : 160 int32 phase-1 done flags (sentinel 1)
  //   [493184, 493568)     flags2  : 96 int32 phase-2 done flags (sentinel 1)
  //   [493568, 493952)     partials: 96 f32 per-anchor loss terms
  int* counts     = (int*)(ws);
  float* fnorm    = (float*)(ws + 1024);
  int* flags1     = (int*)(ws + 492544);
  int* flags2     = (int*)(ws + 493184);
  float* partials = (float*)(ws + 493568);

  fused_kernel<<<160, 512, 0, stream>>>((const int4*)labels, feat, counts,
                                        fnorm, flags1, flags2, partials, out);
}

// Round 6
// 196.800 us; speedup vs baseline: 1.0644x; 1.0644x over previous
//
#include <hip/hip_runtime.h>
#include <stdint.h>

// LocalContrastiveLoss: exact reproduction of the JAX reference, including
// threefry2x32 PRNG (partitionable mode — verified bit-exact, absmax 0) and
// lax.top_k tie-breaking (lower index wins on equal values).
//
// Shapes: features (B=8, C=256, H=128, W=128) f32; labels (8,128,128) i32.
// Output: single f32 scalar.
//
// R6 = R4 revert (best measured: 195.9 µs). R5's single-kernel grid-handshake
// regressed to 209 µs: device-scope acquire/release across non-coherent XCD
// L2s cost more than the inter-dispatch barrier it replaced (fused_kernel ran
// 141 µs at 0.3% VALUBusy, 10 MB FETCH from repeated L2 invalidation).
// Lesson: for sub-10 µs producer->consumer stages spanning the grid, two
// launches beat one grid-sync kernel on CDNA4.
//
//   K1 topk+gather: 160 blocks (s,b,c) x 512 thr — top-3 + counts, then
//      gather + L2-normalize the block's own 3 sampled vectors. Zeroes the
//      loss accumulator/ticket (ws is re-poisoned 0xAA before every call).
//   K2 loss+final: 96 blocks (b,c,p) x 256 thr — 42-slot reduction computing
//      mu inline (dot(a,unit(mean v)) = (a·Σv)/3 / max(‖Σv‖/3,eps)), masked
//      log terms, atomicAdd + ticket; last block writes the scalar.

namespace {

constexpr int Nn = 16384;   // H*W

// ---------------- threefry2x32 (matches jax/_src/prng.py exactly) ----------
__device__ __forceinline__ uint32_t rotl32(uint32_t v, int d) {
  return (v << d) | (v >> (32 - d));
}

__device__ __forceinline__ void threefry2x32(uint32_t k0, uint32_t k1,
                                             uint32_t x0, uint32_t x1,
                                             uint32_t& o0, uint32_t& o1) {
  uint32_t ks2 = k0 ^ k1 ^ 0x1BD11BDAu;
  x0 += k0; x1 += k1;
#define TF_R(d) { x0 += x1; x1 = rotl32(x1, (d)); x1 ^= x0; }
  TF_R(13) TF_R(15) TF_R(26) TF_R(6)
  x0 += k1; x1 += ks2 + 1u;
  TF_R(17) TF_R(29) TF_R(16) TF_R(24)
  x0 += ks2; x1 += k0 + 2u;
  TF_R(13) TF_R(15) TF_R(26) TF_R(6)
  x0 += k0; x1 += k1 + 3u;
  TF_R(17) TF_R(29) TF_R(16) TF_R(24)
  x0 += k1; x1 += ks2 + 4u;
  TF_R(13) TF_R(15) TF_R(26) TF_R(6)
  x0 += ks2; x1 += k0 + 5u;
#undef TF_R
  o0 = x0; o1 = x1;
}

// insert candidate into sorted (descending) top-3 list; key==0 never inserts
__device__ __forceinline__ void ins3(unsigned long long t[3], unsigned long long k) {
  if (k > t[0])      { t[2] = t[1]; t[1] = t[0]; t[0] = k; }
  else if (k > t[1]) { t[2] = t[1]; t[1] = k; }
  else if (k > t[2]) { t[2] = k; }
}

// ---------------- K1: top-3 + counts + fused gather/normalize --------------
// Packed rank key: (uniform_float_bits << 32) | (0xFFFFFFFF - pixel_index).
// float bits ((bits>>9)|0x3f800000) are monotone in the uniform value; the
// complemented index reproduces lax.top_k's lower-index-wins tie rule.
// Branchless threefry (exec-mask makes the conditional cost the same).
__global__ void topk_gather_kernel(const int4* __restrict__ labels4,
                                   const float* __restrict__ feat,
                                   int* __restrict__ counts,
                                   float* __restrict__ fnorm,
                                   float* __restrict__ acc,
                                   int* __restrict__ ticket) {
  const int g = blockIdx.x;          // 160: g = s*32 + b*4 + c
  const int s = g >> 5;
  const int b = (g >> 2) & 7;
  const int c = g & 3;

  if (g == 0 && threadIdx.x == 0) { acc[0] = 0.f; ticket[0] = 0; }

  // subkey = jax.random.split(key(42), 5)[s]
  uint32_t sk0, sk1;
  threefry2x32(0u, 42u, 0u, (uint32_t)s, sk0, sk1);

  unsigned long long t[3] = {0ull, 0ull, 0ull};
  int cnt = 0;
  const int4* row = labels4 + b * (Nn / 4);
  const uint32_t jbase = (uint32_t)((b * 4 + c) * Nn);
#pragma unroll 4
  for (int it = 0; it < 8; ++it) {           // 512 thr x 8 = 4096 int4
    const int i4 = threadIdx.x + it * 512;
    const int4 L = row[i4];
    const int la[4] = {L.x, L.y, L.z, L.w};
#pragma unroll
    for (int e = 0; e < 4; ++e) {
      const uint32_t n = (uint32_t)(i4 * 4 + e);
      uint32_t r0, r1;
      threefry2x32(sk0, sk1, 0u, jbase + n, r0, r1);
      const uint32_t bits = r0 ^ r1;                 // partitionable 32-bit draw
      const uint32_t fb = (bits >> 9) | 0x3f800000u; // uniform float bits [1,2)
      const bool m = (la[e] == c);
      const unsigned long long key =
          m ? (((unsigned long long)fb << 32) |
               (unsigned long long)(0xFFFFFFFFu - n))
            : 0ull;
      cnt += m ? 1 : 0;
      ins3(t, key);
    }
  }

  // wave (64-lane) reduction, then 8-wave merge
  for (int off = 32; off > 0; off >>= 1) {
    unsigned long long o0 = __shfl_down(t[0], (unsigned)off);
    unsigned long long o1 = __shfl_down(t[1], (unsigned)off);
    unsigned long long o2 = __shfl_down(t[2], (unsigned)off);
    int oc = __shfl_down(cnt, (unsigned)off);
    ins3(t, o0); ins3(t, o1); ins3(t, o2);
    cnt += oc;
  }
  __shared__ unsigned long long sm[8][3];
  __shared__ int sc[8];
  __shared__ int sidx[3];
  __shared__ float sr[4][3];
  const int lane = threadIdx.x & 63;
  const int wave = threadIdx.x >> 6;
  if (lane == 0) { sm[wave][0] = t[0]; sm[wave][1] = t[1]; sm[wave][2] = t[2]; sc[wave] = cnt; }
  __syncthreads();
  if (threadIdx.x == 0) {
    unsigned long long f[3] = {sm[0][0], sm[0][1], sm[0][2]};
    int tot = sc[0];
    for (int w = 1; w < 8; ++w) {
      ins3(f, sm[w][0]); ins3(f, sm[w][1]); ins3(f, sm[w][2]);
      tot += sc[w];
    }
#pragma unroll
    for (int r = 0; r < 3; ++r) {
      // empty slot (key==0): index irrelevant (masked downstream), use 0
      sidx[r] = (f[r] == 0ull) ? 0
                : (int)(0xFFFFFFFFu - (uint32_t)(f[r] & 0xFFFFFFFFull));
    }
    if (s == 0) counts[b * 4 + c] = tot;
  }
  __syncthreads();

  // fused gather + per-pixel L2 normalize (threads 0..255; waves 0..3)
  float v[3];
  if (threadIdx.x < 256) {
    const int ch = threadIdx.x;
    float ss[3];
#pragma unroll
    for (int r = 0; r < 3; ++r) {
      v[r] = feat[((b << 8) + ch) * Nn + sidx[r]];
      ss[r] = v[r] * v[r];
    }
    for (int off = 32; off > 0; off >>= 1) {
#pragma unroll
      for (int r = 0; r < 3; ++r) ss[r] += __shfl_down(ss[r], (unsigned)off);
    }
    if (lane == 0) {
#pragma unroll
      for (int r = 0; r < 3; ++r) sr[wave][r] = ss[r];
    }
  }
  __syncthreads();
  if (threadIdx.x < 256) {
    const int ch = threadIdx.x;
#pragma unroll
    for (int r = 0; r < 3; ++r) {
      const float nrm = fmaxf(sqrtf(sr[0][r] + sr[1][r] + sr[2][r] + sr[3][r]), 1e-12f);
      fnorm[(g * 3 + r) * 256 + ch] = v[r] / nrm;
    }
  }
}

// ---------------- K2: loss terms + mu inline + atomic finalize -------------
// fnorm layout: [(s*32 + b*4 + c)*3 + r]*256 + ch,  s: 0=pos1, 1=neg1,
// 2=pos2-anchors, 3=mu2-source, 4=neg2.
__global__ void loss_kernel(const float* __restrict__ fnorm,
                            const int* __restrict__ counts,
                            float* __restrict__ acc,
                            int* __restrict__ ticket,
                            float* __restrict__ out) {
  const int g = blockIdx.x;          // 96 = 8*4*3
  const int b = g / 12;
  const int c = (g % 12) / 3;
  const int p = g % 3;
  const int ch = threadIdx.x;
  const int bc = b * 4 + c;

  const float a1 = fnorm[(bc * 3 + p) * 256 + ch];           // s=0 anchor
  const float a2 = fnorm[((64 + bc) * 3 + p) * 256 + ch];    // s=2 anchor

  // f1sum = sum of the 3 normalized s=0 vectors of (b,c)
  const float f1 = fnorm[(bc * 3 + 0) * 256 + ch] +
                   fnorm[(bc * 3 + 1) * 256 + ch] +
                   fnorm[(bc * 3 + 2) * 256 + ch];

  float part[42];
  part[0] = a1 * f1;                  // a1 . f1sum
  part[1] = f1 * f1;                  // ||f1sum||^2
  // [2..13] dot(a1, neg1[b,e,k])   (s=1)
#pragma unroll
  for (int e = 0; e < 4; ++e)
#pragma unroll
    for (int k = 0; k < 3; ++k)
      part[2 + e * 3 + k] = a1 * fnorm[((32 + b * 4 + e) * 3 + k) * 256 + ch];
  // [14..29] per b2: a2 . f2sum[b2], ||f2sum[b2]||^2   (s=3)
#pragma unroll
  for (int b2 = 0; b2 < 8; ++b2) {
    const int ib = (96 + b2 * 4 + c) * 3;
    const float f2 = fnorm[(ib + 0) * 256 + ch] +
                     fnorm[(ib + 1) * 256 + ch] +
                     fnorm[(ib + 2) * 256 + ch];
    part[14 + 2 * b2]     = a2 * f2;
    part[14 + 2 * b2 + 1] = f2 * f2;
  }
  // [30..41] dot(a2, neg2[b,e,k])  (s=4)
#pragma unroll
  for (int e = 0; e < 4; ++e)
#pragma unroll
    for (int k = 0; k < 3; ++k)
      part[30 + e * 3 + k] = a2 * fnorm[((128 + b * 4 + e) * 3 + k) * 256 + ch];

  for (int off = 32; off > 0; off >>= 1) {
#pragma unroll
    for (int i = 0; i < 42; ++i) part[i] += __shfl_down(part[i], (unsigned)off);
  }
  __shared__ float red[4][42];
  const int lane = threadIdx.x & 63, wave = threadIdx.x >> 6;
  if (lane == 0) {
#pragma unroll
    for (int i = 0; i < 42; ++i) red[wave][i] = part[i];
  }
  __syncthreads();

  if (threadIdx.x == 0) {
    float d[42];
#pragma unroll
    for (int i = 0; i < 42; ++i) d[i] = red[0][i] + red[1][i] + red[2][i] + red[3][i];

    int cb[4];
    for (int e = 0; e < 4; ++e) cb[e] = counts[b * 4 + e];
    bool has_neg = false;
    for (int e = 0; e < 4; ++e) if (e != c && cb[e] > 0) has_neg = true;
    const bool valid_anchor = (cb[c] >= 3) && has_neg;

    float sn1 = 0.f, sn2 = 0.f;
    for (int e = 0; e < 4; ++e) {
      if (e == c) continue;
      int km = cb[e] < 3 ? cb[e] : 3;
      for (int k = 0; k < km; ++k) {
        sn1 += expf(d[2 + e * 3 + k] * 10.0f);
        sn2 += expf(d[30 + e * 3 + k] * 10.0f);
      }
    }
    float term = 0.f;
    if (valid_anchor) {
      // dot(a1, mu1) = (a1.f1sum)/3 / max(||f1sum||/3, eps)
      const float d0 = (d[0] / 3.0f) / fmaxf(sqrtf(d[1]) / 3.0f, 1e-8f);
      const float sp1 = expf(d0 * 10.0f);
      term -= logf(sp1 / (sp1 + sn1 + 1e-8f));
      for (int b2 = 0; b2 < 8; ++b2) {
        if (b2 == b) continue;
        if (counts[b2 * 4 + c] >= 3) {
          const float d2 = (d[14 + 2 * b2] / 3.0f) /
                           fmaxf(sqrtf(d[14 + 2 * b2 + 1]) / 3.0f, 1e-8f);
          const float sp2 = expf(d2 * 10.0f);
          term -= logf(sp2 / (sp2 + sn2 + 1e-8f));
        }
      }
    }
    atomicAdd(acc, term);
    __threadfence();
    const int old = atomicAdd(ticket, 1);
    if (old == 95) {
      const float total = atomicAdd(acc, 0.0f);   // coherent read-after-fence
      out[0] = (float)(0.1 * (double)total / (24.0 + 1e-8));  // LAM*loss/(B*P+EPS)
    }
  }
}

}  // namespace

extern "C" void kernel_launch(void* const* d_in, const int* in_sizes, int n_in,
                              void* d_out, int out_size, void* d_ws, size_t ws_size,
                              hipStream_t stream) {
  const float* feat = (const float*)d_in[0];
  const int* labels = (const int*)d_in[1];
  float* out = (float*)d_out;
  char* ws = (char*)d_ws;

  // workspace layout (bytes):
  //   [0, 128)             counts : 8*4 int32 class counts
  //   [1024, 492544)       fnorm  : 480*256 f32 normalized sampled vectors
  //   [492544, 492548)     acc    : f32 loss accumulator
  //   [492548, 492552)     ticket : int32 completion counter
  int* counts  = (int*)(ws);
  float* fnorm = (float*)(ws + 1024);
  float* acc   = (float*)(ws + 492544);
  int* ticket  = (int*)(ws + 492548);

  topk_gather_kernel<<<160, 512, 0, stream>>>((const int4*)labels, feat,
                                              counts, fnorm, acc, ticket);
  loss_kernel<<<96, 256, 0, stream>>>(fnorm, counts, acc, ticket, out);
}